// Round 3
// baseline (1858.606 us; speedup 1.0000x reference)
//
#include <hip/hip_runtime.h>
#include <stdint.h>

// InteractionModel: N=8192, D=512, T=12. All inputs/outputs fp32.
// R2: split-K PV (S=4, fp32 partials + reduce) for occupancy; XOR bank
//     swizzle on all LDS tiles (PV was 16-way conflicted, gemm 8-way).
// Workspace:
//   0M x1b, 8M x2b, 16M x4b        bf16 LN outputs [8192][512]
//  24M x1t, 32M x2t, 40M x4t       bf16 transposed [512][8192]
//  48M Wb (4x512x512 bf16, 2MB)
//  52M Q/F slots (4 x 8MB)         Q_a; F_a written back over Q_a
//  84M P (8192x8192 bf16, 128MB)
// 212M Fpart (S x 16MB fp32) + Lpart (S x 32KB)   [if ws_size allows]

#define DEV __device__ __forceinline__
typedef unsigned short u16;
typedef __bf16 bf16x8 __attribute__((ext_vector_type(8)));
typedef float f32x4 __attribute__((ext_vector_type(4)));

constexpr int NR = 8192;
constexpr int DDIM = 512;
constexpr int TOUT = 12;

DEV u16 f2b(float f) {
  uint32_t u = __builtin_bit_cast(uint32_t, f);
  u += 0x7fffu + ((u >> 16) & 1u);
  return (u16)(u >> 16);
}
DEV float b2f(u16 h) {
  uint32_t u = ((uint32_t)h) << 16;
  return __builtin_bit_cast(float, u);
}

// ---------------- LayerNorm: fp32 in -> bf16 out ----------------
__global__ __launch_bounds__(64) void ln_kernel(
    const float* __restrict__ xp, const float* __restrict__ xm,
    const float* __restrict__ xs, const float* __restrict__ g,
    const float* __restrict__ b, u16* __restrict__ o1, u16* __restrict__ o2,
    u16* __restrict__ o4) {
  int row = blockIdx.x;
  int which = blockIdx.y;
  const float* x = which == 0 ? xp : (which == 1 ? xm : xs);
  u16* o = which == 0 ? o1 : (which == 1 ? o2 : o4);
  int lane = threadIdx.x;
  const float4* xr = (const float4*)(x + (size_t)row * DDIM);
  float4 v0 = xr[lane * 2], v1 = xr[lane * 2 + 1];
  float vals[8] = {v0.x, v0.y, v0.z, v0.w, v1.x, v1.y, v1.z, v1.w};
  float s = 0.f, s2 = 0.f;
  for (int j = 0; j < 8; j++) { s += vals[j]; s2 += vals[j] * vals[j]; }
  for (int off = 1; off < 64; off <<= 1) {
    s += __shfl_xor(s, off);
    s2 += __shfl_xor(s2, off);
  }
  float m = s * (1.0f / DDIM);
  float var = s2 * (1.0f / DDIM) - m * m;
  var = fmaxf(var, 0.f);
  float rs = rsqrtf(var + 1e-6f);
  int d0 = lane * 8;
  u16 us[8];
  for (int j = 0; j < 8; j++)
    us[j] = f2b((vals[j] - m) * rs * g[d0 + j] + b[d0 + j]);
  uint4 pk;
  pk.x = (uint32_t)us[0] | ((uint32_t)us[1] << 16);
  pk.y = (uint32_t)us[2] | ((uint32_t)us[3] << 16);
  pk.z = (uint32_t)us[4] | ((uint32_t)us[5] << 16);
  pk.w = (uint32_t)us[6] | ((uint32_t)us[7] << 16);
  *(uint4*)(o + (size_t)row * DDIM + d0) = pk;
}

// ---------------- W fp32 -> bf16 ----------------
__global__ __launch_bounds__(256) void wconv_kernel(
    const float* __restrict__ W1, const float* __restrict__ W2,
    const float* __restrict__ W3, const float* __restrict__ W4,
    u16* __restrict__ Wb) {
  int wi = blockIdx.y;
  const float* W = wi == 0 ? W1 : (wi == 1 ? W2 : (wi == 2 ? W3 : W4));
  size_t base = ((size_t)blockIdx.x * 256 + threadIdx.x) * 8;
  const float4* src = (const float4*)(W + base);
  float4 a = src[0], c = src[1];
  float vals[8] = {a.x, a.y, a.z, a.w, c.x, c.y, c.z, c.w};
  u16 us[8];
  for (int j = 0; j < 8; j++) us[j] = f2b(vals[j]);
  uint4 pk;
  pk.x = (uint32_t)us[0] | ((uint32_t)us[1] << 16);
  pk.y = (uint32_t)us[2] | ((uint32_t)us[3] << 16);
  pk.z = (uint32_t)us[4] | ((uint32_t)us[5] << 16);
  pk.w = (uint32_t)us[6] | ((uint32_t)us[7] << 16);
  *(uint4*)(Wb + (size_t)wi * DDIM * DDIM + base) = pk;
}

// ---------------- bf16 transpose [8192][512] -> [512][8192] ----------------
__global__ __launch_bounds__(256) void transpose_kernel(
    const u16* __restrict__ s1, const u16* __restrict__ s2,
    const u16* __restrict__ s4, u16* __restrict__ t1, u16* __restrict__ t2,
    u16* __restrict__ t4) {
  constexpr int LD = 66;
  __shared__ u16 tile[64 * LD];
  int which = blockIdx.z;
  const u16* src = which == 0 ? s1 : (which == 1 ? s2 : s4);
  u16* dst = which == 0 ? t1 : (which == 1 ? t2 : t4);
  int c0 = blockIdx.x * 64;
  int r0 = blockIdx.y * 64;
  int tid = threadIdx.x;
  for (int c = tid; c < 512; c += 256) {
    int i = c >> 3, j8 = (c & 7) * 8;
    uint4 v = *(const uint4*)(src + (size_t)(r0 + i) * DDIM + c0 + j8);
    uint32_t* dw = (uint32_t*)&tile[i * LD + j8];
    dw[0] = v.x; dw[1] = v.y; dw[2] = v.z; dw[3] = v.w;
  }
  __syncthreads();
  for (int c = tid; c < 512; c += 256) {
    int o = c >> 3, e8 = (c & 7) * 8;
    u16 us[8];
    for (int k = 0; k < 8; k++) us[k] = tile[(e8 + k) * LD + o];
    uint4 pk;
    pk.x = (uint32_t)us[0] | ((uint32_t)us[1] << 16);
    pk.y = (uint32_t)us[2] | ((uint32_t)us[3] << 16);
    pk.z = (uint32_t)us[4] | ((uint32_t)us[5] << 16);
    pk.w = (uint32_t)us[6] | ((uint32_t)us[7] << 16);
    *(uint4*)(dst + (size_t)(c0 + o) * NR + r0 + e8) = pk;
  }
}

// ---------------- shared bt-GEMM core (BM=BN=128, BK=32, 2x2 wave grid) ----
// XOR-swizzled LDS: slot (row, c) holds global chunk (row, c ^ (row&3)).
// MODE 0: out bf16 = acc + bias[col]   MODE 1: out bf16 = exp(acc - 48)
template <int MODE>
DEV void gemm_core(const u16* __restrict__ A, const u16* __restrict__ B,
                   u16* __restrict__ C, const float* __restrict__ bias, int K,
                   int lda, int ldb, int ldc, int bx, int by) {
  constexpr int BM = 128, BN = 128, TM = 4, TN = 4;
  __shared__ u16 Asm[BM * 32];
  __shared__ u16 Bsm[BN * 32];
  int tid = threadIdx.x;
  int w = tid >> 6, lane = tid & 63;
  int q = lane >> 4, c16 = lane & 15;
  int n0 = bx * BN, m0 = by * BM;
  int wrow = (w >> 1) * 64, wcol = (w & 1) * 64;
  f32x4 acc[TM][TN] = {};
  for (int k0 = 0; k0 < K; k0 += 32) {
    __syncthreads();
    for (int call = w; call < 16; call += 4) {
      bool isA = call < 8;
      int ci = isA ? call : call - 8;
      int chunk = ci * 64 + lane;
      int row = chunk >> 2;
      int koff = ((chunk & 3) ^ (row & 3)) * 8;  // source swizzle
      const u16* gp = isA ? (A + (size_t)(m0 + row) * lda + k0 + koff)
                          : (B + (size_t)(n0 + row) * ldb + k0 + koff);
      u16* lp = (isA ? Asm : Bsm) + ci * 512;  // wave-uniform base
      __builtin_amdgcn_global_load_lds(
          (const __attribute__((address_space(1))) void*)gp,
          (__attribute__((address_space(3))) void*)lp, 16, 0, 0);
    }
    __syncthreads();
    bf16x8 af[TM], bfr[TN];
    for (int i = 0; i < TM; i++) {
      int r = wrow + i * 16 + c16;
      af[i] = *(const bf16x8*)&Asm[r * 32 + ((q ^ (r & 3)) * 8)];
    }
    for (int n = 0; n < TN; n++) {
      int r = wcol + n * 16 + c16;
      bfr[n] = *(const bf16x8*)&Bsm[r * 32 + ((q ^ (r & 3)) * 8)];
    }
    for (int i = 0; i < TM; i++)
      for (int n = 0; n < TN; n++)
        acc[i][n] = __builtin_amdgcn_mfma_f32_16x16x32_bf16(af[i], bfr[n],
                                                            acc[i][n], 0, 0, 0);
  }
  for (int i = 0; i < TM; i++) {
    for (int n = 0; n < TN; n++) {
      int col = n0 + wcol + n * 16 + c16;
      float bv = 0.f;
      if constexpr (MODE == 0) bv = bias[col];
      for (int r = 0; r < 4; r++) {
        int row = m0 + wrow + i * 16 + q * 4 + r;
        float v = acc[i][n][r];
        if constexpr (MODE == 0) v += bv;
        if constexpr (MODE == 1) v = __expf(v - 48.0f);
        C[(size_t)row * ldc + col] = f2b(v);
      }
    }
  }
}

// scores: P = exp(Q K^T - 48)
__global__ __launch_bounds__(256, 2) void scores_kernel(
    const u16* __restrict__ Q, const u16* __restrict__ Kv,
    u16* __restrict__ P) {
  gemm_core<1>(Q, Kv, P, nullptr, DDIM, DDIM, DDIM, NR, blockIdx.x,
               blockIdx.y);
}

// qproj (z-batched): Q_z = X_z W_z^T + b_z
__global__ __launch_bounds__(256, 2) void qproj_kernel(
    const u16* __restrict__ s0, const u16* __restrict__ s1,
    const u16* __restrict__ s2, const u16* __restrict__ s3,
    const u16* __restrict__ Wb, const float* __restrict__ b0,
    const float* __restrict__ b1, const float* __restrict__ b2,
    const float* __restrict__ b3, u16* __restrict__ Qs) {
  int z = blockIdx.z;
  const u16* A = z == 0 ? s0 : (z == 1 ? s1 : (z == 2 ? s2 : s3));
  const float* bias = z == 0 ? b0 : (z == 1 ? b1 : (z == 2 ? b2 : b3));
  gemm_core<0>(A, Wb + (size_t)z * DDIM * DDIM, Qs + (size_t)z * NR * DDIM,
               bias, DDIM, DDIM, DDIM, DDIM, blockIdx.x, blockIdx.y);
}

// ---------------- PV: F = (P V) / (l sqrt(512)) ----------------
// BM=64, BN=256, BK=64, 4 waves 1x4; split-K over blockIdx.z.
// PART: fp32 partials + Lpart.  !PART: direct bf16 (single split).
template <bool PART>
__global__ __launch_bounds__(256, 4) void pv_kernel_t(
    const u16* __restrict__ A,  // P [8192][8192]
    const u16* __restrict__ B,  // V^T [512][8192]
    u16* __restrict__ C,        // F [8192][512] bf16 (direct mode)
    float* __restrict__ Fpart, float* __restrict__ Lpart, int kLen) {
  constexpr int BM = 64, BN = 256, BK = 64;
  __shared__ u16 Asm[BM * BK];  // 8 KB
  __shared__ u16 Bsm[BN * BK];  // 32 KB
  int tid = threadIdx.x, w = tid >> 6, lane = tid & 63;
  int q = lane >> 4, c16 = lane & 15;
  int n0 = blockIdx.x * BN, m0 = blockIdx.y * BM;
  int kz = blockIdx.z;
  int kbeg = kz * kLen;
  int wcol = w * 64;
  f32x4 acc[4][4] = {};
  f32x4 accl[4];
  for (int i = 0; i < 4; i++) accl[i] = f32x4{0.f, 0.f, 0.f, 0.f};
  bf16x8 ones;
  for (int j = 0; j < 8; j++) ones[j] = (__bf16)1.0f;
  for (int k0 = kbeg; k0 < kbeg + kLen; k0 += BK) {
    __syncthreads();
    for (int it = 0; it < 10; it++) {
      int cb = it * 256 + w * 64;  // wave-uniform
      int c = cb + lane;
      bool isA = cb < 512;  // uniform per wave (512 % 64 == 0)
      int ci = isA ? c : c - 512;
      int row = ci >> 3;
      int koff = ((ci & 7) ^ (row & 7)) * 8;  // source swizzle
      const u16* gp = isA ? (A + (size_t)(m0 + row) * NR + k0 + koff)
                          : (B + (size_t)(n0 + row) * NR + k0 + koff);
      u16* lp = isA ? (Asm + (size_t)cb * 8) : (Bsm + (size_t)(cb - 512) * 8);
      __builtin_amdgcn_global_load_lds(
          (const __attribute__((address_space(1))) void*)gp,
          (__attribute__((address_space(3))) void*)lp, 16, 0, 0);
    }
    __syncthreads();
    for (int kh = 0; kh < 2; kh++) {
      bf16x8 af[4], bfr[4];
      int cl = kh * 4 + q;
      for (int i = 0; i < 4; i++) {
        int r = i * 16 + c16;
        af[i] = *(const bf16x8*)&Asm[r * BK + ((cl ^ (r & 7)) * 8)];
      }
      for (int n = 0; n < 4; n++) {
        int r = wcol + n * 16 + c16;
        bfr[n] = *(const bf16x8*)&Bsm[r * BK + ((cl ^ (r & 7)) * 8)];
      }
      for (int i = 0; i < 4; i++)
        accl[i] = __builtin_amdgcn_mfma_f32_16x16x32_bf16(af[i], ones, accl[i],
                                                          0, 0, 0);
      for (int i = 0; i < 4; i++)
        for (int n = 0; n < 4; n++)
          acc[i][n] = __builtin_amdgcn_mfma_f32_16x16x32_bf16(
              af[i], bfr[n], acc[i][n], 0, 0, 0);
    }
  }
  if constexpr (PART) {
    float* Fp = Fpart + (size_t)kz * NR * DDIM;
    for (int i = 0; i < 4; i++)
      for (int n = 0; n < 4; n++) {
        int col = n0 + wcol + n * 16 + c16;
        for (int r = 0; r < 4; r++) {
          int row = m0 + i * 16 + q * 4 + r;
          Fp[(size_t)row * DDIM + col] = acc[i][n][r];
        }
      }
    if (w == 0 && c16 == 0)
      for (int i = 0; i < 4; i++)
        for (int r = 0; r < 4; r++)
          Lpart[(size_t)kz * NR + m0 + i * 16 + q * 4 + r] = accl[i][r];
  } else {
    for (int i = 0; i < 4; i++) {
      float invl[4];
      for (int r = 0; r < 4; r++)
        invl[r] = 0.044194173824159216f / accl[i][r];  // 1/(l*sqrt(512))
      for (int n = 0; n < 4; n++) {
        int col = n0 + wcol + n * 16 + c16;
        for (int r = 0; r < 4; r++) {
          int row = m0 + i * 16 + q * 4 + r;
          C[(size_t)row * DDIM + col] = f2b(acc[i][n][r] * invl[r]);
        }
      }
    }
  }
}

// ---------------- split-K reduce: F = (sum_s Fpart) / (l sqrt(512)) -------
__global__ __launch_bounds__(256) void reduce_kernel(
    const float* __restrict__ Fpart, const float* __restrict__ Lpart,
    u16* __restrict__ F, int S) {
  int tid = threadIdx.x;
  int row = blockIdx.x * 2 + (tid >> 7);
  int c4 = (tid & 127) * 4;
  float l = 0.f;
  for (int s = 0; s < S; s++) l += Lpart[(size_t)s * NR + row];
  float sx = 0.f, sy = 0.f, sz = 0.f, sw = 0.f;
  for (int s = 0; s < S; s++) {
    float4 v = *(const float4*)&Fpart[((size_t)s * NR + row) * DDIM + c4];
    sx += v.x; sy += v.y; sz += v.z; sw += v.w;
  }
  float inv = 0.044194173824159216f / l;
  u16 o0 = f2b(sx * inv), o1 = f2b(sy * inv), o2 = f2b(sz * inv),
      o3 = f2b(sw * inv);
  uint2 pk;
  pk.x = (uint32_t)o0 | ((uint32_t)o1 << 16);
  pk.y = (uint32_t)o2 | ((uint32_t)o3 << 16);
  *(uint2*)&F[(size_t)row * DDIM + c4] = pk;
}

// ---------------- fused head: concat+relu+Wp+bias+gate ----------------
__global__ __launch_bounds__(256) void head_kernel(
    const u16* __restrict__ F1, const u16* __restrict__ F2,
    const u16* __restrict__ F3, const u16* __restrict__ F4,
    const u16* __restrict__ x1, const u16* __restrict__ x2,
    const u16* __restrict__ x4, const float* __restrict__ Wp,
    const float* __restrict__ bp, const float* __restrict__ tg,
    const float* __restrict__ Wt1, const float* __restrict__ bt1,
    const float* __restrict__ Wt2, const float* __restrict__ bt2,
    float* __restrict__ out) {
  __shared__ float wps[TOUT * 2 * DDIM];
  __shared__ float t2s;
  int tid = threadIdx.x;
  for (int i = tid; i < TOUT * 2 * DDIM; i += 256) wps[i] = Wp[i];
  if (tid == 0) {
    float s = bt2[0];
    for (int k = 0; k < 50; k++) s += Wt2[k] * (tg[0] * Wt1[k] + bt1[k]);
    t2s = 1.0f / (1.0f + __expf(-s));
  }
  __syncthreads();
  int g = tid >> 5, j = tid & 31;
  size_t m = (size_t)blockIdx.x * 8 + g;
  float a12[TOUT] = {}, a34[TOUT] = {};
  for (int d = j; d < 2 * DDIM; d += 32) {
    float h12, h34;
    if (d < DDIM) {
      float xv = b2f(x1[m * DDIM + d]);
      h12 = b2f(F1[m * DDIM + d]) + xv;
      h34 = b2f(F3[m * DDIM + d]) + xv;
    } else {
      int dd = d - DDIM;
      h12 = b2f(F2[m * DDIM + dd]) + b2f(x2[m * DDIM + dd]);
      h34 = b2f(F4[m * DDIM + dd]) + b2f(x4[m * DDIM + dd]);
    }
    h12 = fmaxf(h12, 0.f);
    h34 = fmaxf(h34, 0.f);
    for (int t = 0; t < TOUT; t++) {
      float wv = wps[t * 2 * DDIM + d];
      a12[t] += h12 * wv;
      a34[t] += h34 * wv;
    }
  }
  for (int off = 1; off < 32; off <<= 1)
    for (int t = 0; t < TOUT; t++) {
      a12[t] += __shfl_xor(a12[t], off);
      a34[t] += __shfl_xor(a34[t], off);
    }
  if (j < TOUT) {
    float t2 = t2s;
    out[m * TOUT + j] = t2 * a12[j] + (1.f - t2) * a34[j] + bp[j];
  }
}

extern "C" void kernel_launch(void* const* d_in, const int* in_sizes, int n_in,
                              void* d_out, int out_size, void* d_ws,
                              size_t ws_size, hipStream_t stream) {
  (void)in_sizes; (void)n_in; (void)out_size;
  const float* xp = (const float*)d_in[0];
  const float* xm = (const float*)d_in[1];
  const float* xs = (const float*)d_in[2];
  const float* ln_g = (const float*)d_in[3];
  const float* ln_b = (const float*)d_in[4];
  const float* Wmat[4] = {(const float*)d_in[5], (const float*)d_in[7],
                          (const float*)d_in[9], (const float*)d_in[11]};
  const float* bvec[4] = {(const float*)d_in[6], (const float*)d_in[8],
                          (const float*)d_in[10], (const float*)d_in[12]};
  const float* Wp = (const float*)d_in[13];
  const float* bp = (const float*)d_in[14];
  const float* tg = (const float*)d_in[15];
  const float* Wt1 = (const float*)d_in[16];
  const float* bt1 = (const float*)d_in[17];
  const float* Wt2 = (const float*)d_in[18];
  const float* bt2 = (const float*)d_in[19];
  float* out = (float*)d_out;

  char* ws = (char*)d_ws;
  const size_t MB = 1ull << 20;
  u16* x1b = (u16*)(ws + 0 * MB);
  u16* x2b = (u16*)(ws + 8 * MB);
  u16* x4b = (u16*)(ws + 16 * MB);
  u16* x1t = (u16*)(ws + 24 * MB);
  u16* x2t = (u16*)(ws + 32 * MB);
  u16* x4t = (u16*)(ws + 40 * MB);
  u16* Wb = (u16*)(ws + 48 * MB);
  u16* Qs = (u16*)(ws + 52 * MB);  // 4 slots of 8 MB; F_a overlays Q_a
  u16* P = (u16*)(ws + 84 * MB);   // 128 MiB

  // split-K scratch (gated on ws_size): Fpart S x 16MB fp32, Lpart S x 32KB
  int S = 1;
  if (ws_size >= 277 * MB) S = 4;
  else if (ws_size >= 245 * MB) S = 2;
  float* Fpart = (float*)(ws + 212 * MB);
  float* Lpart = (float*)(ws + 212 * MB + (size_t)S * 16 * MB);

  ln_kernel<<<dim3(NR, 3), 64, 0, stream>>>(xp, xm, xs, ln_g, ln_b, x1b, x2b,
                                            x4b);
  wconv_kernel<<<dim3(128, 4), 256, 0, stream>>>(Wmat[0], Wmat[1], Wmat[2],
                                                 Wmat[3], Wb);
  transpose_kernel<<<dim3(8, 128, 3), 256, 0, stream>>>(x1b, x2b, x4b, x1t,
                                                        x2t, x4t);
  qproj_kernel<<<dim3(DDIM / 128, NR / 128, 4), 256, 0, stream>>>(
      x1b, x2b, x1b, x4b, Wb, bvec[0], bvec[1], bvec[2], bvec[3], Qs);

  const u16* kvb[4] = {x2b, x1b, x4b, x1b};
  const u16* kvt[4] = {x2t, x1t, x4t, x1t};
  u16* slot[4];
  for (int a = 0; a < 4; a++) slot[a] = Qs + (size_t)a * NR * DDIM;

  for (int a = 0; a < 4; a++) {
    scores_kernel<<<dim3(NR / 128, NR / 128), 256, 0, stream>>>(slot[a],
                                                                kvb[a], P);
    if (S > 1) {
      pv_kernel_t<true><<<dim3(DDIM / 256, NR / 64, S), 256, 0, stream>>>(
          P, kvt[a], nullptr, Fpart, Lpart, NR / S);
      reduce_kernel<<<dim3(NR / 2), 256, 0, stream>>>(Fpart, Lpart, slot[a],
                                                      S);
    } else {
      pv_kernel_t<false><<<dim3(DDIM / 256, NR / 64, 1), 256, 0, stream>>>(
          P, kvt[a], slot[a], nullptr, nullptr, NR);
    }
  }

  // attention a -> f[fidx[a]]: a0->f2, a1->f1, a2->f4, a3->f3
  head_kernel<<<dim3(NR / 8), 256, 0, stream>>>(
      slot[1], slot[0], slot[3], slot[2], x1b, x2b, x4b, Wp, bp, tg, Wt1, bt1,
      Wt2, bt2, out);
}

// Round 4
// 1535.078 us; speedup vs baseline: 1.2108x; 1.2108x over previous
//
#include <hip/hip_runtime.h>
#include <stdint.h>

// InteractionModel: N=8192, D=512, T=12. All inputs/outputs fp32.
// R4: PV double-buffered LDS pipeline (stage k+1 || compute k) at BM=64/
//     BN=256 — fixes the 1-block/CU exposed-drain stall (800 GB/s in R2/R3).
//     Row-sum l moved to scores epilogue (atomicAdd); PV loses ones-MFMA.
//     Split-K reverted (R3 regression: +traffic, no real co-residency gain).
// Workspace (212 MB):
//   0M x1b, 8M x2b, 16M x4b        bf16 LN outputs [8192][512]
//  24M x1t, 32M x2t, 40M x4t       bf16 transposed [512][8192]
//  48M Wb (4x512x512 bf16, 2MB)    50M lsum (8192 fp32, reused per attn)
//  52M Q/F slots (4 x 8MB)         Q_a; F_a written back over Q_a
//  84M P (8192x8192 bf16, 128MB)

#define DEV __device__ __forceinline__
typedef unsigned short u16;
typedef __bf16 bf16x8 __attribute__((ext_vector_type(8)));
typedef float f32x4 __attribute__((ext_vector_type(4)));

constexpr int NR = 8192;
constexpr int DDIM = 512;
constexpr int TOUT = 12;

DEV u16 f2b(float f) {
  uint32_t u = __builtin_bit_cast(uint32_t, f);
  u += 0x7fffu + ((u >> 16) & 1u);
  return (u16)(u >> 16);
}
DEV float b2f(u16 h) {
  uint32_t u = ((uint32_t)h) << 16;
  return __builtin_bit_cast(float, u);
}

// ---------------- LayerNorm: fp32 in -> bf16 out ----------------
__global__ __launch_bounds__(64) void ln_kernel(
    const float* __restrict__ xp, const float* __restrict__ xm,
    const float* __restrict__ xs, const float* __restrict__ g,
    const float* __restrict__ b, u16* __restrict__ o1, u16* __restrict__ o2,
    u16* __restrict__ o4) {
  int row = blockIdx.x;
  int which = blockIdx.y;
  const float* x = which == 0 ? xp : (which == 1 ? xm : xs);
  u16* o = which == 0 ? o1 : (which == 1 ? o2 : o4);
  int lane = threadIdx.x;
  const float4* xr = (const float4*)(x + (size_t)row * DDIM);
  float4 v0 = xr[lane * 2], v1 = xr[lane * 2 + 1];
  float vals[8] = {v0.x, v0.y, v0.z, v0.w, v1.x, v1.y, v1.z, v1.w};
  float s = 0.f, s2 = 0.f;
  for (int j = 0; j < 8; j++) { s += vals[j]; s2 += vals[j] * vals[j]; }
  for (int off = 1; off < 64; off <<= 1) {
    s += __shfl_xor(s, off);
    s2 += __shfl_xor(s2, off);
  }
  float m = s * (1.0f / DDIM);
  float var = s2 * (1.0f / DDIM) - m * m;
  var = fmaxf(var, 0.f);
  float rs = rsqrtf(var + 1e-6f);
  int d0 = lane * 8;
  u16 us[8];
  for (int j = 0; j < 8; j++)
    us[j] = f2b((vals[j] - m) * rs * g[d0 + j] + b[d0 + j]);
  uint4 pk;
  pk.x = (uint32_t)us[0] | ((uint32_t)us[1] << 16);
  pk.y = (uint32_t)us[2] | ((uint32_t)us[3] << 16);
  pk.z = (uint32_t)us[4] | ((uint32_t)us[5] << 16);
  pk.w = (uint32_t)us[6] | ((uint32_t)us[7] << 16);
  *(uint4*)(o + (size_t)row * DDIM + d0) = pk;
}

// ---------------- W fp32 -> bf16 ----------------
__global__ __launch_bounds__(256) void wconv_kernel(
    const float* __restrict__ W1, const float* __restrict__ W2,
    const float* __restrict__ W3, const float* __restrict__ W4,
    u16* __restrict__ Wb) {
  int wi = blockIdx.y;
  const float* W = wi == 0 ? W1 : (wi == 1 ? W2 : (wi == 2 ? W3 : W4));
  size_t base = ((size_t)blockIdx.x * 256 + threadIdx.x) * 8;
  const float4* src = (const float4*)(W + base);
  float4 a = src[0], c = src[1];
  float vals[8] = {a.x, a.y, a.z, a.w, c.x, c.y, c.z, c.w};
  u16 us[8];
  for (int j = 0; j < 8; j++) us[j] = f2b(vals[j]);
  uint4 pk;
  pk.x = (uint32_t)us[0] | ((uint32_t)us[1] << 16);
  pk.y = (uint32_t)us[2] | ((uint32_t)us[3] << 16);
  pk.z = (uint32_t)us[4] | ((uint32_t)us[5] << 16);
  pk.w = (uint32_t)us[6] | ((uint32_t)us[7] << 16);
  *(uint4*)(Wb + (size_t)wi * DDIM * DDIM + base) = pk;
}

// ---------------- bf16 transpose [8192][512] -> [512][8192] ----------------
__global__ __launch_bounds__(256) void transpose_kernel(
    const u16* __restrict__ s1, const u16* __restrict__ s2,
    const u16* __restrict__ s4, u16* __restrict__ t1, u16* __restrict__ t2,
    u16* __restrict__ t4) {
  constexpr int LD = 66;
  __shared__ u16 tile[64 * LD];
  int which = blockIdx.z;
  const u16* src = which == 0 ? s1 : (which == 1 ? s2 : s4);
  u16* dst = which == 0 ? t1 : (which == 1 ? t2 : t4);
  int c0 = blockIdx.x * 64;
  int r0 = blockIdx.y * 64;
  int tid = threadIdx.x;
  for (int c = tid; c < 512; c += 256) {
    int i = c >> 3, j8 = (c & 7) * 8;
    uint4 v = *(const uint4*)(src + (size_t)(r0 + i) * DDIM + c0 + j8);
    uint32_t* dw = (uint32_t*)&tile[i * LD + j8];
    dw[0] = v.x; dw[1] = v.y; dw[2] = v.z; dw[3] = v.w;
  }
  __syncthreads();
  for (int c = tid; c < 512; c += 256) {
    int o = c >> 3, e8 = (c & 7) * 8;
    u16 us[8];
    for (int k = 0; k < 8; k++) us[k] = tile[(e8 + k) * LD + o];
    uint4 pk;
    pk.x = (uint32_t)us[0] | ((uint32_t)us[1] << 16);
    pk.y = (uint32_t)us[2] | ((uint32_t)us[3] << 16);
    pk.z = (uint32_t)us[4] | ((uint32_t)us[5] << 16);
    pk.w = (uint32_t)us[6] | ((uint32_t)us[7] << 16);
    *(uint4*)(dst + (size_t)(c0 + o) * NR + r0 + e8) = pk;
  }
}

// ---------------- shared bt-GEMM core (BM=BN=128, BK=32, 2x2 wave grid) ----
// XOR-swizzled LDS: slot (row, c) holds global chunk (row, c ^ (row&3)).
// MODE 0: out bf16 = acc + bias[col]
// MODE 1: out bf16 = exp(acc - 48); row-sums atomicAdd'ed into lsum
template <int MODE>
DEV void gemm_core(const u16* __restrict__ A, const u16* __restrict__ B,
                   u16* __restrict__ C, const float* __restrict__ bias,
                   float* __restrict__ lsum, int K, int lda, int ldb, int ldc,
                   int bx, int by) {
  constexpr int BM = 128, BN = 128, TM = 4, TN = 4;
  __shared__ u16 Asm[BM * 32];
  __shared__ u16 Bsm[BN * 32];
  int tid = threadIdx.x;
  int w = tid >> 6, lane = tid & 63;
  int q = lane >> 4, c16 = lane & 15;
  int n0 = bx * BN, m0 = by * BM;
  int wrow = (w >> 1) * 64, wcol = (w & 1) * 64;
  f32x4 acc[TM][TN] = {};
  for (int k0 = 0; k0 < K; k0 += 32) {
    __syncthreads();
    for (int call = w; call < 16; call += 4) {
      bool isA = call < 8;
      int ci = isA ? call : call - 8;
      int chunk = ci * 64 + lane;
      int row = chunk >> 2;
      int koff = ((chunk & 3) ^ (row & 3)) * 8;  // source swizzle
      const u16* gp = isA ? (A + (size_t)(m0 + row) * lda + k0 + koff)
                          : (B + (size_t)(n0 + row) * ldb + k0 + koff);
      u16* lp = (isA ? Asm : Bsm) + ci * 512;  // wave-uniform base
      __builtin_amdgcn_global_load_lds(
          (const __attribute__((address_space(1))) void*)gp,
          (__attribute__((address_space(3))) void*)lp, 16, 0, 0);
    }
    __syncthreads();
    bf16x8 af[TM], bfr[TN];
    for (int i = 0; i < TM; i++) {
      int r = wrow + i * 16 + c16;
      af[i] = *(const bf16x8*)&Asm[r * 32 + ((q ^ (r & 3)) * 8)];
    }
    for (int n = 0; n < TN; n++) {
      int r = wcol + n * 16 + c16;
      bfr[n] = *(const bf16x8*)&Bsm[r * 32 + ((q ^ (r & 3)) * 8)];
    }
    for (int i = 0; i < TM; i++)
      for (int n = 0; n < TN; n++)
        acc[i][n] = __builtin_amdgcn_mfma_f32_16x16x32_bf16(af[i], bfr[n],
                                                            acc[i][n], 0, 0, 0);
  }
  float rs[TM][4];
  if constexpr (MODE == 1)
    for (int i = 0; i < TM; i++)
      for (int r = 0; r < 4; r++) rs[i][r] = 0.f;
  for (int i = 0; i < TM; i++) {
    for (int n = 0; n < TN; n++) {
      int col = n0 + wcol + n * 16 + c16;
      float bv = 0.f;
      if constexpr (MODE == 0) bv = bias[col];
      for (int r = 0; r < 4; r++) {
        int row = m0 + wrow + i * 16 + q * 4 + r;
        float v = acc[i][n][r];
        if constexpr (MODE == 0) v += bv;
        if constexpr (MODE == 1) {
          v = __expf(v - 48.0f);
          rs[i][r] += v;
        }
        C[(size_t)row * ldc + col] = f2b(v);
      }
    }
  }
  if constexpr (MODE == 1) {
    // reduce rs across the 16 c16-lanes (lane bits 0..3), then atomicAdd
    for (int i = 0; i < TM; i++)
      for (int r = 0; r < 4; r++) {
        float v = rs[i][r];
        v += __shfl_xor(v, 1);
        v += __shfl_xor(v, 2);
        v += __shfl_xor(v, 4);
        v += __shfl_xor(v, 8);
        if (c16 == 0)
          atomicAdd(&lsum[m0 + wrow + i * 16 + q * 4 + r], v);
      }
  }
}

// scores: P = exp(Q K^T - 48), l += rowsum(P)
__global__ __launch_bounds__(256, 2) void scores_kernel(
    const u16* __restrict__ Q, const u16* __restrict__ Kv,
    u16* __restrict__ P, float* __restrict__ lsum) {
  gemm_core<1>(Q, Kv, P, nullptr, lsum, DDIM, DDIM, DDIM, NR, blockIdx.x,
               blockIdx.y);
}

// qproj (z-batched): Q_z = X_z W_z^T + b_z
__global__ __launch_bounds__(256, 2) void qproj_kernel(
    const u16* __restrict__ s0, const u16* __restrict__ s1,
    const u16* __restrict__ s2, const u16* __restrict__ s3,
    const u16* __restrict__ Wb, const float* __restrict__ b0,
    const float* __restrict__ b1, const float* __restrict__ b2,
    const float* __restrict__ b3, u16* __restrict__ Qs) {
  int z = blockIdx.z;
  const u16* A = z == 0 ? s0 : (z == 1 ? s1 : (z == 2 ? s2 : s3));
  const float* bias = z == 0 ? b0 : (z == 1 ? b1 : (z == 2 ? b2 : b3));
  gemm_core<0>(A, Wb + (size_t)z * DDIM * DDIM, Qs + (size_t)z * NR * DDIM,
               bias, nullptr, DDIM, DDIM, DDIM, DDIM, blockIdx.x, blockIdx.y);
}

// ---------------- PV: F = (P V) / (l sqrt(512)), double-buffered ----------
// BM=64, BN=256, BK=64, 4 waves 1x4 ([64x64] wave tiles). grid (2,128).
// Pipeline: stage(k+1 -> buf^1) issued BEFORE compute(buf) each iter, so the
// barrier-drain overlaps the MFMA+LDS phase (1 block/CU: no implicit overlap).
__global__ __launch_bounds__(256, 2) void pv_db_kernel(
    const u16* __restrict__ A,     // P [8192][8192]
    const u16* __restrict__ B,     // V^T [512][8192]
    const float* __restrict__ lsum,
    u16* __restrict__ C) {         // F [8192][512]
  constexpr int BM = 64, BN = 256, BK = 64;
  __shared__ u16 Asm[2][BM * BK];  // 2 x 8 KB
  __shared__ u16 Bsm[2][BN * BK];  // 2 x 32 KB
  int tid = threadIdx.x, w = tid >> 6, lane = tid & 63;
  int q = lane >> 4, c16 = lane & 15;
  int n0 = blockIdx.x * BN, m0 = blockIdx.y * BM;
  int wcol = w * 64;
  f32x4 acc[4][4] = {};

  auto stage = [&](int k0, int buf) {
    for (int it = 0; it < 10; it++) {
      int cb = it * 256 + w * 64;  // wave-uniform
      int c = cb + lane;
      bool isA = cb < 512;  // uniform per wave (512 % 64 == 0)
      int ci = isA ? c : c - 512;
      int row = ci >> 3;
      int koff = ((ci & 7) ^ (row & 7)) * 8;  // source swizzle
      const u16* gp = isA ? (A + (size_t)(m0 + row) * NR + k0 + koff)
                          : (B + (size_t)(n0 + row) * NR + k0 + koff);
      u16* lp = isA ? (&Asm[buf][0] + (size_t)cb * 8)
                    : (&Bsm[buf][0] + (size_t)(cb - 512) * 8);
      __builtin_amdgcn_global_load_lds(
          (const __attribute__((address_space(1))) void*)gp,
          (__attribute__((address_space(3))) void*)lp, 16, 0, 0);
    }
  };

  stage(0, 0);
  __syncthreads();
  constexpr int KSTEPS = NR / BK;
  for (int ks = 0; ks < KSTEPS; ks++) {
    int cur = ks & 1;
    if (ks + 1 < KSTEPS) stage((ks + 1) * BK, cur ^ 1);  // prefetch in flight
    for (int kh = 0; kh < 2; kh++) {
      bf16x8 af[4], bfr[4];
      int cl = kh * 4 + q;
      for (int i = 0; i < 4; i++) {
        int r = i * 16 + c16;
        af[i] = *(const bf16x8*)&Asm[cur][r * BK + ((cl ^ (r & 7)) * 8)];
      }
      for (int n = 0; n < 4; n++) {
        int r = wcol + n * 16 + c16;
        bfr[n] = *(const bf16x8*)&Bsm[cur][r * BK + ((cl ^ (r & 7)) * 8)];
      }
      for (int i = 0; i < 4; i++)
        for (int n = 0; n < 4; n++)
          acc[i][n] = __builtin_amdgcn_mfma_f32_16x16x32_bf16(
              af[i], bfr[n], acc[i][n], 0, 0, 0);
    }
    __syncthreads();  // drains prefetch loads (overlapped with compute above)
  }
  for (int i = 0; i < 4; i++) {
    float invl[4];
    for (int r = 0; r < 4; r++)
      invl[r] =
          0.044194173824159216f / lsum[m0 + i * 16 + q * 4 + r];  // 1/(l*sqrt512)
    for (int n = 0; n < 4; n++) {
      int col = n0 + wcol + n * 16 + c16;
      for (int r = 0; r < 4; r++) {
        int row = m0 + i * 16 + q * 4 + r;
        C[(size_t)row * DDIM + col] = f2b(acc[i][n][r] * invl[r]);
      }
    }
  }
}

// ---------------- fused head: concat+relu+Wp+bias+gate ----------------
__global__ __launch_bounds__(256) void head_kernel(
    const u16* __restrict__ F1, const u16* __restrict__ F2,
    const u16* __restrict__ F3, const u16* __restrict__ F4,
    const u16* __restrict__ x1, const u16* __restrict__ x2,
    const u16* __restrict__ x4, const float* __restrict__ Wp,
    const float* __restrict__ bp, const float* __restrict__ tg,
    const float* __restrict__ Wt1, const float* __restrict__ bt1,
    const float* __restrict__ Wt2, const float* __restrict__ bt2,
    float* __restrict__ out) {
  __shared__ float wps[TOUT * 2 * DDIM];
  __shared__ float t2s;
  int tid = threadIdx.x;
  for (int i = tid; i < TOUT * 2 * DDIM; i += 256) wps[i] = Wp[i];
  if (tid == 0) {
    float s = bt2[0];
    for (int k = 0; k < 50; k++) s += Wt2[k] * (tg[0] * Wt1[k] + bt1[k]);
    t2s = 1.0f / (1.0f + __expf(-s));
  }
  __syncthreads();
  int g = tid >> 5, j = tid & 31;
  size_t m = (size_t)blockIdx.x * 8 + g;
  float a12[TOUT] = {}, a34[TOUT] = {};
  for (int d = j; d < 2 * DDIM; d += 32) {
    float h12, h34;
    if (d < DDIM) {
      float xv = b2f(x1[m * DDIM + d]);
      h12 = b2f(F1[m * DDIM + d]) + xv;
      h34 = b2f(F3[m * DDIM + d]) + xv;
    } else {
      int dd = d - DDIM;
      h12 = b2f(F2[m * DDIM + dd]) + b2f(x2[m * DDIM + dd]);
      h34 = b2f(F4[m * DDIM + dd]) + b2f(x4[m * DDIM + dd]);
    }
    h12 = fmaxf(h12, 0.f);
    h34 = fmaxf(h34, 0.f);
    for (int t = 0; t < TOUT; t++) {
      float wv = wps[t * 2 * DDIM + d];
      a12[t] += h12 * wv;
      a34[t] += h34 * wv;
    }
  }
  for (int off = 1; off < 32; off <<= 1)
    for (int t = 0; t < TOUT; t++) {
      a12[t] += __shfl_xor(a12[t], off);
      a34[t] += __shfl_xor(a34[t], off);
    }
  if (j < TOUT) {
    float t2 = t2s;
    out[m * TOUT + j] = t2 * a12[j] + (1.f - t2) * a34[j] + bp[j];
  }
}

extern "C" void kernel_launch(void* const* d_in, const int* in_sizes, int n_in,
                              void* d_out, int out_size, void* d_ws,
                              size_t ws_size, hipStream_t stream) {
  (void)in_sizes; (void)n_in; (void)out_size; (void)ws_size;
  const float* xp = (const float*)d_in[0];
  const float* xm = (const float*)d_in[1];
  const float* xs = (const float*)d_in[2];
  const float* ln_g = (const float*)d_in[3];
  const float* ln_b = (const float*)d_in[4];
  const float* Wmat[4] = {(const float*)d_in[5], (const float*)d_in[7],
                          (const float*)d_in[9], (const float*)d_in[11]};
  const float* bvec[4] = {(const float*)d_in[6], (const float*)d_in[8],
                          (const float*)d_in[10], (const float*)d_in[12]};
  const float* Wp = (const float*)d_in[13];
  const float* bp = (const float*)d_in[14];
  const float* tg = (const float*)d_in[15];
  const float* Wt1 = (const float*)d_in[16];
  const float* bt1 = (const float*)d_in[17];
  const float* Wt2 = (const float*)d_in[18];
  const float* bt2 = (const float*)d_in[19];
  float* out = (float*)d_out;

  char* ws = (char*)d_ws;
  const size_t MB = 1ull << 20;
  u16* x1b = (u16*)(ws + 0 * MB);
  u16* x2b = (u16*)(ws + 8 * MB);
  u16* x4b = (u16*)(ws + 16 * MB);
  u16* x1t = (u16*)(ws + 24 * MB);
  u16* x2t = (u16*)(ws + 32 * MB);
  u16* x4t = (u16*)(ws + 40 * MB);
  u16* Wb = (u16*)(ws + 48 * MB);
  float* lsum = (float*)(ws + 50 * MB);  // 8192 fp32, reused per attention
  u16* Qs = (u16*)(ws + 52 * MB);        // 4 slots of 8 MB; F_a overlays Q_a
  u16* P = (u16*)(ws + 84 * MB);         // 128 MiB

  ln_kernel<<<dim3(NR, 3), 64, 0, stream>>>(xp, xm, xs, ln_g, ln_b, x1b, x2b,
                                            x4b);
  wconv_kernel<<<dim3(128, 4), 256, 0, stream>>>(Wmat[0], Wmat[1], Wmat[2],
                                                 Wmat[3], Wb);
  transpose_kernel<<<dim3(8, 128, 3), 256, 0, stream>>>(x1b, x2b, x4b, x1t,
                                                        x2t, x4t);
  qproj_kernel<<<dim3(DDIM / 128, NR / 128, 4), 256, 0, stream>>>(
      x1b, x2b, x1b, x4b, Wb, bvec[0], bvec[1], bvec[2], bvec[3], Qs);

  const u16* kvb[4] = {x2b, x1b, x4b, x1b};
  const u16* kvt[4] = {x2t, x1t, x4t, x1t};
  u16* slot[4];
  for (int a = 0; a < 4; a++) slot[a] = Qs + (size_t)a * NR * DDIM;

  for (int a = 0; a < 4; a++) {
    hipMemsetAsync(lsum, 0, NR * sizeof(float), stream);
    scores_kernel<<<dim3(NR / 128, NR / 128), 256, 0, stream>>>(
        slot[a], kvb[a], P, lsum);
    // PV writes F_a over Q_a's slot (Q_a dead after scores_a)
    pv_db_kernel<<<dim3(DDIM / 256, NR / 64), 256, 0, stream>>>(P, kvt[a],
                                                                lsum, slot[a]);
  }

  // attention a -> f[fidx[a]]: a0->f2, a1->f1, a2->f4, a3->f3
  head_kernel<<<dim3(NR / 8), 256, 0, stream>>>(
      slot[1], slot[0], slot[3], slot[2], x1b, x2b, x4b, Wp, bp, tg, Wt1, bt1,
      Wt2, bt2, out);
}

// Round 5
// 1167.881 us; speedup vs baseline: 1.5914x; 1.3144x over previous
//
#include <hip/hip_runtime.h>
#include <stdint.h>

// InteractionModel: N=8192, D=512, T=12. All inputs/outputs fp32.
// R5: (1) lsum back to PV ones-MFMA (R4 scores atomic epilogue cost 77us);
//     (2) correct BK=32 LDS swizzle s=(q+(r>>1))&3 (R4's was 4-way conflicted);
//     (3) combo dispatch: pv_a (blocks 0..255) || scores_{a+1} (blocks 256+)
//         with ping-pong P buffers, gated on ws_size >= 340MB.
// Workspace (dual-P): 0 x1b, 8 x2b, 16 x4b | 24/32/40 x1t/x2t/x4t |
//   48 Wb | 52 Qs (4x8MB, F_a overlays Q_a) | 84 P0 (128MB) | 212 P1 (128MB)

#define DEV __device__ __forceinline__
typedef unsigned short u16;
typedef __bf16 bf16x8 __attribute__((ext_vector_type(8)));
typedef float f32x4 __attribute__((ext_vector_type(4)));

constexpr int NR = 8192;
constexpr int DDIM = 512;
constexpr int TOUT = 12;

DEV u16 f2b(float f) {
  uint32_t u = __builtin_bit_cast(uint32_t, f);
  u += 0x7fffu + ((u >> 16) & 1u);
  return (u16)(u >> 16);
}
DEV float b2f(u16 h) {
  uint32_t u = ((uint32_t)h) << 16;
  return __builtin_bit_cast(float, u);
}

// ---------------- LayerNorm: fp32 in -> bf16 out ----------------
__global__ __launch_bounds__(64) void ln_kernel(
    const float* __restrict__ xp, const float* __restrict__ xm,
    const float* __restrict__ xs, const float* __restrict__ g,
    const float* __restrict__ b, u16* __restrict__ o1, u16* __restrict__ o2,
    u16* __restrict__ o4) {
  int row = blockIdx.x;
  int which = blockIdx.y;
  const float* x = which == 0 ? xp : (which == 1 ? xm : xs);
  u16* o = which == 0 ? o1 : (which == 1 ? o2 : o4);
  int lane = threadIdx.x;
  const float4* xr = (const float4*)(x + (size_t)row * DDIM);
  float4 v0 = xr[lane * 2], v1 = xr[lane * 2 + 1];
  float vals[8] = {v0.x, v0.y, v0.z, v0.w, v1.x, v1.y, v1.z, v1.w};
  float s = 0.f, s2 = 0.f;
  for (int j = 0; j < 8; j++) { s += vals[j]; s2 += vals[j] * vals[j]; }
  for (int off = 1; off < 64; off <<= 1) {
    s += __shfl_xor(s, off);
    s2 += __shfl_xor(s2, off);
  }
  float m = s * (1.0f / DDIM);
  float var = s2 * (1.0f / DDIM) - m * m;
  var = fmaxf(var, 0.f);
  float rs = rsqrtf(var + 1e-6f);
  int d0 = lane * 8;
  u16 us[8];
  for (int j = 0; j < 8; j++)
    us[j] = f2b((vals[j] - m) * rs * g[d0 + j] + b[d0 + j]);
  uint4 pk;
  pk.x = (uint32_t)us[0] | ((uint32_t)us[1] << 16);
  pk.y = (uint32_t)us[2] | ((uint32_t)us[3] << 16);
  pk.z = (uint32_t)us[4] | ((uint32_t)us[5] << 16);
  pk.w = (uint32_t)us[6] | ((uint32_t)us[7] << 16);
  *(uint4*)(o + (size_t)row * DDIM + d0) = pk;
}

// ---------------- W fp32 -> bf16 ----------------
__global__ __launch_bounds__(256) void wconv_kernel(
    const float* __restrict__ W1, const float* __restrict__ W2,
    const float* __restrict__ W3, const float* __restrict__ W4,
    u16* __restrict__ Wb) {
  int wi = blockIdx.y;
  const float* W = wi == 0 ? W1 : (wi == 1 ? W2 : (wi == 2 ? W3 : W4));
  size_t base = ((size_t)blockIdx.x * 256 + threadIdx.x) * 8;
  const float4* src = (const float4*)(W + base);
  float4 a = src[0], c = src[1];
  float vals[8] = {a.x, a.y, a.z, a.w, c.x, c.y, c.z, c.w};
  u16 us[8];
  for (int j = 0; j < 8; j++) us[j] = f2b(vals[j]);
  uint4 pk;
  pk.x = (uint32_t)us[0] | ((uint32_t)us[1] << 16);
  pk.y = (uint32_t)us[2] | ((uint32_t)us[3] << 16);
  pk.z = (uint32_t)us[4] | ((uint32_t)us[5] << 16);
  pk.w = (uint32_t)us[6] | ((uint32_t)us[7] << 16);
  *(uint4*)(Wb + (size_t)wi * DDIM * DDIM + base) = pk;
}

// ---------------- bf16 transpose [8192][512] -> [512][8192] ----------------
__global__ __launch_bounds__(256) void transpose_kernel(
    const u16* __restrict__ s1, const u16* __restrict__ s2,
    const u16* __restrict__ s4, u16* __restrict__ t1, u16* __restrict__ t2,
    u16* __restrict__ t4) {
  constexpr int LD = 66;
  __shared__ u16 tile[64 * LD];
  int which = blockIdx.z;
  const u16* src = which == 0 ? s1 : (which == 1 ? s2 : s4);
  u16* dst = which == 0 ? t1 : (which == 1 ? t2 : t4);
  int c0 = blockIdx.x * 64;
  int r0 = blockIdx.y * 64;
  int tid = threadIdx.x;
  for (int c = tid; c < 512; c += 256) {
    int i = c >> 3, j8 = (c & 7) * 8;
    uint4 v = *(const uint4*)(src + (size_t)(r0 + i) * DDIM + c0 + j8);
    uint32_t* dw = (uint32_t*)&tile[i * LD + j8];
    dw[0] = v.x; dw[1] = v.y; dw[2] = v.z; dw[3] = v.w;
  }
  __syncthreads();
  for (int c = tid; c < 512; c += 256) {
    int o = c >> 3, e8 = (c & 7) * 8;
    u16 us[8];
    for (int k = 0; k < 8; k++) us[k] = tile[(e8 + k) * LD + o];
    uint4 pk;
    pk.x = (uint32_t)us[0] | ((uint32_t)us[1] << 16);
    pk.y = (uint32_t)us[2] | ((uint32_t)us[3] << 16);
    pk.z = (uint32_t)us[4] | ((uint32_t)us[5] << 16);
    pk.w = (uint32_t)us[6] | ((uint32_t)us[7] << 16);
    *(uint4*)(dst + (size_t)(c0 + o) * NR + r0 + e8) = pk;
  }
}

// ---------------- shared bt-GEMM core (BM=BN=128, BK=32, 2x2 wave grid) ----
// LDS slot (row,s) holds global chunk (s-(row>>1))&3; reader uses
// s=(q+(r>>1))&3 -> bank-group (4r+s)%8 covers all 8 -> 2-way (free).
// MODE 0: out bf16 = acc + bias[col]   MODE 1: out bf16 = exp(acc - 48)
// lds: 8192 u16 (A first 4096, B next 4096)
template <int MODE>
DEV void gemm_core(const u16* __restrict__ A, const u16* __restrict__ B,
                   u16* __restrict__ C, const float* __restrict__ bias,
                   u16* lds, int K, int lda, int ldb, int ldc, int bx,
                   int by) {
  constexpr int TM = 4, TN = 4;
  u16* Asm = lds;
  u16* Bsm = lds + 4096;
  int tid = threadIdx.x;
  int w = tid >> 6, lane = tid & 63;
  int q = lane >> 4, c16 = lane & 15;
  int n0 = bx * 128, m0 = by * 128;
  int wrow = (w >> 1) * 64, wcol = (w & 1) * 64;
  f32x4 acc[TM][TN] = {};
  for (int k0 = 0; k0 < K; k0 += 32) {
    __syncthreads();
    for (int call = w; call < 16; call += 4) {
      bool isA = call < 8;
      int ci = isA ? call : call - 8;
      int chunk = ci * 64 + lane;
      int row = chunk >> 2;
      int gch = ((chunk & 3) - (row >> 1)) & 3;  // source chunk for this slot
      const u16* gp = isA ? (A + (size_t)(m0 + row) * lda + k0 + gch * 8)
                          : (B + (size_t)(n0 + row) * ldb + k0 + gch * 8);
      u16* lp = (isA ? Asm : Bsm) + ci * 512;  // wave-uniform base
      __builtin_amdgcn_global_load_lds(
          (const __attribute__((address_space(1))) void*)gp,
          (__attribute__((address_space(3))) void*)lp, 16, 0, 0);
    }
    __syncthreads();
    bf16x8 af[TM], bfr[TN];
    for (int i = 0; i < TM; i++) {
      int r = wrow + i * 16 + c16;
      af[i] = *(const bf16x8*)&Asm[r * 32 + (((q + (r >> 1)) & 3) * 8)];
    }
    for (int n = 0; n < TN; n++) {
      int r = wcol + n * 16 + c16;
      bfr[n] = *(const bf16x8*)&Bsm[r * 32 + (((q + (r >> 1)) & 3) * 8)];
    }
    for (int i = 0; i < TM; i++)
      for (int n = 0; n < TN; n++)
        acc[i][n] = __builtin_amdgcn_mfma_f32_16x16x32_bf16(af[i], bfr[n],
                                                            acc[i][n], 0, 0, 0);
  }
  for (int i = 0; i < TM; i++) {
    for (int n = 0; n < TN; n++) {
      int col = n0 + wcol + n * 16 + c16;
      float bv = 0.f;
      if constexpr (MODE == 0) bv = bias[col];
      for (int r = 0; r < 4; r++) {
        int row = m0 + wrow + i * 16 + q * 4 + r;
        float v = acc[i][n][r];
        if constexpr (MODE == 0) v += bv;
        if constexpr (MODE == 1) v = __expf(v - 48.0f);
        C[(size_t)row * ldc + col] = f2b(v);
      }
    }
  }
}

// ---------------- PV body: F = (P V)/(l sqrt512), double-buffered ----------
// BM=64, BN=256, BK=64; l via ones-MFMA. lds: 40960 u16 (80 KB):
// A dbuf [0,8192), B dbuf [8192,40960).
DEV void pv_body(const u16* __restrict__ A, const u16* __restrict__ B,
                 u16* lds, u16* __restrict__ C, int bx, int by) {
  constexpr int BM = 64, BN = 256, BK = 64;
  int tid = threadIdx.x, w = tid >> 6, lane = tid & 63;
  int q = lane >> 4, c16 = lane & 15;
  int n0 = bx * BN, m0 = by * BM;
  int wcol = w * 64;
  f32x4 acc[4][4] = {};
  f32x4 accl[4];
  for (int i = 0; i < 4; i++) accl[i] = f32x4{0.f, 0.f, 0.f, 0.f};
  bf16x8 ones;
  for (int j = 0; j < 8; j++) ones[j] = (__bf16)1.0f;

  auto stage = [&](int k0, int buf) {
    for (int it = 0; it < 10; it++) {
      int cb = it * 256 + w * 64;  // wave-uniform
      int c = cb + lane;
      bool isA = cb < 512;  // uniform per wave (512 % 64 == 0)
      int ci = isA ? c : c - 512;
      int row = ci >> 3;
      int koff = ((ci & 7) ^ (row & 7)) * 8;  // full 8-group swizzle
      const u16* gp = isA ? (A + (size_t)(m0 + row) * NR + k0 + koff)
                          : (B + (size_t)(n0 + row) * NR + k0 + koff);
      u16* lp = isA ? (lds + buf * 4096 + cb * 8)
                    : (lds + 8192 + buf * 16384 + (cb - 512) * 8);
      __builtin_amdgcn_global_load_lds(
          (const __attribute__((address_space(1))) void*)gp,
          (__attribute__((address_space(3))) void*)lp, 16, 0, 0);
    }
  };

  stage(0, 0);
  __syncthreads();
  constexpr int KSTEPS = NR / BK;
  for (int ks = 0; ks < KSTEPS; ks++) {
    int cur = ks & 1;
    if (ks + 1 < KSTEPS) stage((ks + 1) * BK, cur ^ 1);  // prefetch in flight
    const u16* Asm = lds + cur * 4096;
    const u16* Bsm = lds + 8192 + cur * 16384;
    for (int kh = 0; kh < 2; kh++) {
      bf16x8 af[4], bfr[4];
      int cl = kh * 4 + q;
      for (int i = 0; i < 4; i++) {
        int r = i * 16 + c16;
        af[i] = *(const bf16x8*)&Asm[r * BK + ((cl ^ (r & 7)) * 8)];
      }
      for (int n = 0; n < 4; n++) {
        int r = wcol + n * 16 + c16;
        bfr[n] = *(const bf16x8*)&Bsm[r * BK + ((cl ^ (r & 7)) * 8)];
      }
      for (int i = 0; i < 4; i++)
        accl[i] = __builtin_amdgcn_mfma_f32_16x16x32_bf16(af[i], ones, accl[i],
                                                          0, 0, 0);
      for (int i = 0; i < 4; i++)
        for (int n = 0; n < 4; n++)
          acc[i][n] = __builtin_amdgcn_mfma_f32_16x16x32_bf16(
              af[i], bfr[n], acc[i][n], 0, 0, 0);
    }
    __syncthreads();
  }
  for (int i = 0; i < 4; i++) {
    float invl[4];
    for (int r = 0; r < 4; r++)
      invl[r] = 0.044194173824159216f / accl[i][r];  // 1/(l*sqrt(512))
    for (int n = 0; n < 4; n++) {
      int col = n0 + wcol + n * 16 + c16;
      for (int r = 0; r < 4; r++) {
        int row = m0 + i * 16 + q * 4 + r;
        C[(size_t)row * DDIM + col] = f2b(acc[i][n][r] * invl[r]);
      }
    }
  }
}

// scores: P = exp(Q K^T - 48)   grid (64,64)
__global__ __launch_bounds__(256, 4) void scores_kernel(
    const u16* __restrict__ Q, const u16* __restrict__ Kv,
    u16* __restrict__ P) {
  __shared__ u16 lds[8192];
  gemm_core<1>(Q, Kv, P, nullptr, lds, DDIM, DDIM, DDIM, NR, blockIdx.x,
               blockIdx.y);
}

// qproj (z-batched): Q_z = X_z W_z^T + b_z   grid (4,64,4)
__global__ __launch_bounds__(256, 4) void qproj_kernel(
    const u16* __restrict__ s0, const u16* __restrict__ s1,
    const u16* __restrict__ s2, const u16* __restrict__ s3,
    const u16* __restrict__ Wb, const float* __restrict__ b0,
    const float* __restrict__ b1, const float* __restrict__ b2,
    const float* __restrict__ b3, u16* __restrict__ Qs) {
  __shared__ u16 lds[8192];
  int z = blockIdx.z;
  const u16* A = z == 0 ? s0 : (z == 1 ? s1 : (z == 2 ? s2 : s3));
  const float* bias = z == 0 ? b0 : (z == 1 ? b1 : (z == 2 ? b2 : b3));
  gemm_core<0>(A, Wb + (size_t)z * DDIM * DDIM, Qs + (size_t)z * NR * DDIM,
               bias, lds, DDIM, DDIM, DDIM, DDIM, blockIdx.x, blockIdx.y);
}

// standalone PV   grid (2,128)
__global__ __launch_bounds__(256, 2) void pv_kernel(
    const u16* __restrict__ A, const u16* __restrict__ B,
    u16* __restrict__ C) {
  __shared__ u16 lds[40960];
  pv_body(A, B, lds, C, blockIdx.x, blockIdx.y);
}

// combo: blocks 0..255 -> pv_a (Pin->F); blocks 256..4351 -> scores_{a+1}
__global__ __launch_bounds__(256, 2) void combo_kernel(
    const u16* __restrict__ Pin, const u16* __restrict__ Vt,
    u16* __restrict__ F, const u16* __restrict__ Q,
    const u16* __restrict__ Kv, u16* __restrict__ Pout) {
  __shared__ u16 lds[40960];
  if (blockIdx.x < 256) {
    pv_body(Pin, Vt, lds, F, blockIdx.x & 1, blockIdx.x >> 1);
  } else {
    int b = blockIdx.x - 256;
    gemm_core<1>(Q, Kv, Pout, nullptr, lds, DDIM, DDIM, DDIM, NR, b & 63,
                 b >> 6);
  }
}

// ---------------- fused head: concat+relu+Wp+bias+gate ----------------
__global__ __launch_bounds__(256) void head_kernel(
    const u16* __restrict__ F1, const u16* __restrict__ F2,
    const u16* __restrict__ F3, const u16* __restrict__ F4,
    const u16* __restrict__ x1, const u16* __restrict__ x2,
    const u16* __restrict__ x4, const float* __restrict__ Wp,
    const float* __restrict__ bp, const float* __restrict__ tg,
    const float* __restrict__ Wt1, const float* __restrict__ bt1,
    const float* __restrict__ Wt2, const float* __restrict__ bt2,
    float* __restrict__ out) {
  __shared__ float wps[TOUT * 2 * DDIM];
  __shared__ float t2s;
  int tid = threadIdx.x;
  for (int i = tid; i < TOUT * 2 * DDIM; i += 256) wps[i] = Wp[i];
  if (tid == 0) {
    float s = bt2[0];
    for (int k = 0; k < 50; k++) s += Wt2[k] * (tg[0] * Wt1[k] + bt1[k]);
    t2s = 1.0f / (1.0f + __expf(-s));
  }
  __syncthreads();
  int g = tid >> 5, j = tid & 31;
  size_t m = (size_t)blockIdx.x * 8 + g;
  float a12[TOUT] = {}, a34[TOUT] = {};
  for (int d = j; d < 2 * DDIM; d += 32) {
    float h12, h34;
    if (d < DDIM) {
      float xv = b2f(x1[m * DDIM + d]);
      h12 = b2f(F1[m * DDIM + d]) + xv;
      h34 = b2f(F3[m * DDIM + d]) + xv;
    } else {
      int dd = d - DDIM;
      h12 = b2f(F2[m * DDIM + dd]) + b2f(x2[m * DDIM + dd]);
      h34 = b2f(F4[m * DDIM + dd]) + b2f(x4[m * DDIM + dd]);
    }
    h12 = fmaxf(h12, 0.f);
    h34 = fmaxf(h34, 0.f);
    for (int t = 0; t < TOUT; t++) {
      float wv = wps[t * 2 * DDIM + d];
      a12[t] += h12 * wv;
      a34[t] += h34 * wv;
    }
  }
  for (int off = 1; off < 32; off <<= 1)
    for (int t = 0; t < TOUT; t++) {
      a12[t] += __shfl_xor(a12[t], off);
      a34[t] += __shfl_xor(a34[t], off);
    }
  if (j < TOUT) {
    float t2 = t2s;
    out[m * TOUT + j] = t2 * a12[j] + (1.f - t2) * a34[j] + bp[j];
  }
}

extern "C" void kernel_launch(void* const* d_in, const int* in_sizes, int n_in,
                              void* d_out, int out_size, void* d_ws,
                              size_t ws_size, hipStream_t stream) {
  (void)in_sizes; (void)n_in; (void)out_size;
  const float* xp = (const float*)d_in[0];
  const float* xm = (const float*)d_in[1];
  const float* xs = (const float*)d_in[2];
  const float* ln_g = (const float*)d_in[3];
  const float* ln_b = (const float*)d_in[4];
  const float* Wmat[4] = {(const float*)d_in[5], (const float*)d_in[7],
                          (const float*)d_in[9], (const float*)d_in[11]};
  const float* bvec[4] = {(const float*)d_in[6], (const float*)d_in[8],
                          (const float*)d_in[10], (const float*)d_in[12]};
  const float* Wp = (const float*)d_in[13];
  const float* bp = (const float*)d_in[14];
  const float* tg = (const float*)d_in[15];
  const float* Wt1 = (const float*)d_in[16];
  const float* bt1 = (const float*)d_in[17];
  const float* Wt2 = (const float*)d_in[18];
  const float* bt2 = (const float*)d_in[19];
  float* out = (float*)d_out;

  char* ws = (char*)d_ws;
  const size_t MB = 1ull << 20;
  u16* x1b = (u16*)(ws + 0 * MB);
  u16* x2b = (u16*)(ws + 8 * MB);
  u16* x4b = (u16*)(ws + 16 * MB);
  u16* x1t = (u16*)(ws + 24 * MB);
  u16* x2t = (u16*)(ws + 32 * MB);
  u16* x4t = (u16*)(ws + 40 * MB);
  u16* Wb = (u16*)(ws + 48 * MB);
  u16* Qs = (u16*)(ws + 52 * MB);  // 4 slots of 8 MB; F_a overlays Q_a
  u16* P0 = (u16*)(ws + 84 * MB);  // 128 MiB
  bool dual = ws_size >= 340 * MB;
  u16* P1 = dual ? (u16*)(ws + 212 * MB) : P0;

  ln_kernel<<<dim3(NR, 3), 64, 0, stream>>>(xp, xm, xs, ln_g, ln_b, x1b, x2b,
                                            x4b);
  wconv_kernel<<<dim3(128, 4), 256, 0, stream>>>(Wmat[0], Wmat[1], Wmat[2],
                                                 Wmat[3], Wb);
  transpose_kernel<<<dim3(8, 128, 3), 256, 0, stream>>>(x1b, x2b, x4b, x1t,
                                                        x2t, x4t);
  qproj_kernel<<<dim3(DDIM / 128, NR / 128, 4), 256, 0, stream>>>(
      x1b, x2b, x1b, x4b, Wb, bvec[0], bvec[1], bvec[2], bvec[3], Qs);

  const u16* kvb[4] = {x2b, x1b, x4b, x1b};
  const u16* kvt[4] = {x2t, x1t, x4t, x1t};
  u16* slot[4];
  for (int a = 0; a < 4; a++) slot[a] = Qs + (size_t)a * NR * DDIM;

  if (dual) {
    u16* Pb[4] = {P0, P1, P0, P1};
    scores_kernel<<<dim3(64, 64), 256, 0, stream>>>(slot[0], kvb[0], Pb[0]);
    for (int a = 0; a < 3; a++) {
      // pv_a (P_a -> F_a over Q_a) || scores_{a+1} (-> other P buffer)
      combo_kernel<<<dim3(256 + 64 * 64), 256, 0, stream>>>(
          Pb[a], kvt[a], slot[a], slot[a + 1], kvb[a + 1], Pb[a + 1]);
    }
    pv_kernel<<<dim3(2, 128), 256, 0, stream>>>(Pb[3], kvt[3], slot[3]);
  } else {
    for (int a = 0; a < 4; a++) {
      scores_kernel<<<dim3(64, 64), 256, 0, stream>>>(slot[a], kvb[a], P0);
      pv_kernel<<<dim3(2, 128), 256, 0, stream>>>(P0, kvt[a], slot[a]);
    }
  }

  // attention a -> f[fidx[a]]: a0->f2, a1->f1, a2->f4, a3->f3
  head_kernel<<<dim3(NR / 8), 256, 0, stream>>>(
      slot[1], slot[0], slot[3], slot[2], x1b, x2b, x4b, Wp, bp, tg, Wt1, bt1,
      Wt2, bt2, out);
}